// Round 1
// baseline (620.505 us; speedup 1.0000x reference)
//
#include <hip/hip_runtime.h>

#define B_ 8
#define T_ 24
#define N_ 4096
#define FI 64
#define HH 128
#define CC 192
#define GG 256
#define COLS 32
#define SI 200   // inpT stride (bf16 elems): 400B, 16B-aligned, 2-way bank aliasing (free)
#define SF 133   // hbuf/zbuf stride (f32 elems): odd-ish stride to spread banks
#define SO 68    // out staging stride (f32 elems): 272B, 16B-aligned

typedef __bf16 bf16_t;
typedef bf16_t bf16x8 __attribute__((ext_vector_type(8)));
typedef float  f32x4  __attribute__((ext_vector_type(4)));

static __device__ __forceinline__ f32x4 mfma16(bf16x8 a, bf16x8 b, f32x4 c) {
    return __builtin_amdgcn_mfma_f32_16x16x32_bf16(a, b, c, 0, 0, 0);
}

__global__ __launch_bounds__(256, 2) void mgru_kernel(
    const float* __restrict__ x,
    const float* __restrict__ gate_w,
    const float* __restrict__ gate_b,
    const float* __restrict__ cand_w,
    const float* __restrict__ cand_b,
    const float* __restrict__ out_w,
    const float* __restrict__ out_b,
    float* __restrict__ out)
{
    __shared__ __align__(16) bf16_t inpT[COLS * SI];   // [col][ch]: ch 0..63 = x, 64..191 = h / r*h
    __shared__ __align__(16) float  hbuf[COLS * SF];   // fp32 master h
    __shared__ __align__(16) float  zbuf[COLS * SF];   // z (fp32); reused as out staging
    __shared__ float bias[GG + HH + FI];

    const int tid  = threadIdx.x;
    const int wave = tid >> 6;
    const int lane = tid & 63;
    const int quad = lane >> 4;
    const int l16  = lane & 15;

    const int bb = blockIdx.x >> 7;            // batch index
    const int n0 = (blockIdx.x & 127) * COLS;  // column tile base

    if (tid < GG) bias[tid] = gate_b[tid];
    if (tid < HH) bias[GG + tid] = cand_b[tid];
    if (tid < FI) bias[GG + HH + tid] = out_b[tid];

    for (int i = tid; i < COLS * HH; i += 256) {
        const int col = i >> 7, ch = i & (HH - 1);
        hbuf[col * SF + ch] = 0.0f;
        inpT[col * SI + FI + ch] = (bf16_t)0.0f;
    }

    // ---- preload weights as register-resident MFMA A-fragments (bf16) ----
    // A-layout: lane holds A[m = m0 + (lane&15)][k = k0 + (lane>>4)*8 + j], j=0..7
    bf16x8 gA[4][6];   // gates: this wave's 64 rows (4 M-tiles), K=192 (6 K-tiles)
    #pragma unroll
    for (int i = 0; i < 4; ++i) {
        const int m = wave * 64 + i * 16 + l16;
        #pragma unroll
        for (int kt = 0; kt < 6; ++kt) {
            bf16x8 f;
            #pragma unroll
            for (int j = 0; j < 8; ++j) {
                const int c = kt * 32 + quad * 8 + j;
                f[j] = (bf16_t)gate_w[(m * CC + c) * 2 + 1];  // [:, :, K-1, 0]
            }
            gA[i][kt] = f;
        }
    }
    bf16x8 cA[2][6];   // cand: this wave's 32 rows (2 M-tiles)
    #pragma unroll
    for (int i = 0; i < 2; ++i) {
        const int m = wave * 32 + i * 16 + l16;
        #pragma unroll
        for (int kt = 0; kt < 6; ++kt) {
            bf16x8 f;
            #pragma unroll
            for (int j = 0; j < 8; ++j) {
                const int c = kt * 32 + quad * 8 + j;
                f[j] = (bf16_t)cand_w[(m * CC + c) * 2 + 1];
            }
            cA[i][kt] = f;
        }
    }
    bf16x8 oA[4];      // out proj: this wave's 16 rows (1 M-tile), K=128 (4 K-tiles)
    {
        const int m = wave * 16 + l16;
        #pragma unroll
        for (int kt = 0; kt < 4; ++kt) {
            bf16x8 f;
            #pragma unroll
            for (int j = 0; j < 8; ++j) {
                const int c = kt * 32 + quad * 8 + j;
                f[j] = (bf16_t)out_w[m * HH + c];  // [:, :, 0, 0]
            }
            oA[kt] = f;
        }
    }

    const int xcol = tid >> 3;        // 0..31: column within tile
    const int xcg  = (tid & 7) * 8;   // 8-float group within the 64 features
    const float* xbase = x   + ((size_t)bb * T_ * N_ + n0) * FI;
    float*       obase = out + ((size_t)bb * T_ * N_ + n0) * FI;

    for (int t = 0; t < T_; ++t) {
        // ---- stage x_t tile: coalesced fp32 read -> bf16 LDS [col][ch] ----
        const float* xp = xbase + (size_t)t * N_ * FI + xcol * FI + xcg;
        f32x4 a0 = *(const f32x4*)xp;
        f32x4 a1 = *(const f32x4*)(xp + 4);
        bf16x8 xv;
        xv[0] = (bf16_t)a0[0]; xv[1] = (bf16_t)a0[1];
        xv[2] = (bf16_t)a0[2]; xv[3] = (bf16_t)a0[3];
        xv[4] = (bf16_t)a1[0]; xv[5] = (bf16_t)a1[1];
        xv[6] = (bf16_t)a1[2]; xv[7] = (bf16_t)a1[3];
        *(bf16x8*)&inpT[xcol * SI + xcg] = xv;
        __syncthreads();                                   // 1: x + h ready

        // ---- gates = Wg @ [x; h] ----
        f32x4 acc[4][2];
        #pragma unroll
        for (int i = 0; i < 4; ++i) {
            acc[i][0] = f32x4{0.f, 0.f, 0.f, 0.f};
            acc[i][1] = f32x4{0.f, 0.f, 0.f, 0.f};
        }
        #pragma unroll
        for (int kt = 0; kt < 6; ++kt) {
            const int ko = kt * 32 + quad * 8;
            bf16x8 b0 = *(const bf16x8*)&inpT[l16 * SI + ko];
            bf16x8 b1 = *(const bf16x8*)&inpT[(16 + l16) * SI + ko];
            #pragma unroll
            for (int i = 0; i < 4; ++i) {
                acc[i][0] = mfma16(gA[i][kt], b0, acc[i][0]);
                acc[i][1] = mfma16(gA[i][kt], b1, acc[i][1]);
            }
        }
        // sigmoid in-register; D-layout: row = quad*4+r, col = nt*16 + l16
        float sig[4][2][4];
        #pragma unroll
        for (int i = 0; i < 4; ++i)
        #pragma unroll
        for (int nt = 0; nt < 2; ++nt)
        #pragma unroll
        for (int r = 0; r < 4; ++r) {
            const int row = wave * 64 + i * 16 + quad * 4 + r;
            const float v = acc[i][nt][r] + bias[row];
            sig[i][nt][r] = 1.0f / (1.0f + __expf(-v));
        }
        __syncthreads();                                   // 2: all gate reads of inpT done
        if (wave < 2) {
            // r rows 0..127 -> write r*h (bf16) over the h region of inpT
            #pragma unroll
            for (int i = 0; i < 4; ++i)
            #pragma unroll
            for (int nt = 0; nt < 2; ++nt)
            #pragma unroll
            for (int r = 0; r < 4; ++r) {
                const int ch  = wave * 64 + i * 16 + quad * 4 + r;
                const int col = nt * 16 + l16;
                const float rh = sig[i][nt][r] * hbuf[col * SF + ch];
                inpT[col * SI + FI + ch] = (bf16_t)rh;
            }
        } else {
            // z rows 0..127 -> stash fp32 z
            #pragma unroll
            for (int i = 0; i < 4; ++i)
            #pragma unroll
            for (int nt = 0; nt < 2; ++nt)
            #pragma unroll
            for (int r = 0; r < 4; ++r) {
                const int ch  = (wave - 2) * 64 + i * 16 + quad * 4 + r;
                const int col = nt * 16 + l16;
                zbuf[col * SF + ch] = sig[i][nt][r];
            }
        }
        __syncthreads();                                   // 3: cinp ready

        // ---- cand = Wc @ [x; r*h] ----
        f32x4 cacc[2][2];
        #pragma unroll
        for (int i = 0; i < 2; ++i) {
            cacc[i][0] = f32x4{0.f, 0.f, 0.f, 0.f};
            cacc[i][1] = f32x4{0.f, 0.f, 0.f, 0.f};
        }
        #pragma unroll
        for (int kt = 0; kt < 6; ++kt) {
            const int ko = kt * 32 + quad * 8;
            bf16x8 b0 = *(const bf16x8*)&inpT[l16 * SI + ko];
            bf16x8 b1 = *(const bf16x8*)&inpT[(16 + l16) * SI + ko];
            #pragma unroll
            for (int i = 0; i < 2; ++i) {
                cacc[i][0] = mfma16(cA[i][kt], b0, cacc[i][0]);
                cacc[i][1] = mfma16(cA[i][kt], b1, cacc[i][1]);
            }
        }
        __syncthreads();                                   // 4: all cand reads done
        // tanh + state update (fp32 master), refresh bf16 h in inpT
        #pragma unroll
        for (int i = 0; i < 2; ++i)
        #pragma unroll
        for (int nt = 0; nt < 2; ++nt)
        #pragma unroll
        for (int r = 0; r < 4; ++r) {
            const int ch  = wave * 32 + i * 16 + quad * 4 + r;
            const int col = nt * 16 + l16;
            const float v  = cacc[i][nt][r] + bias[GG + ch];
            const float e  = __expf(2.0f * v);
            const float ht = 1.0f - 2.0f / (e + 1.0f);     // tanh(v), saturates correctly
            const float z  = zbuf[col * SF + ch];
            const float h  = hbuf[col * SF + ch];
            const float hn = (1.0f - z) * h + z * ht;
            hbuf[col * SF + ch] = hn;
            inpT[col * SI + FI + ch] = (bf16_t)hn;
        }
        __syncthreads();                                   // 5: h_t ready

        // ---- o = relu(Wo @ h_t + b), fused epilogue ----
        f32x4 oacc[2];
        oacc[0] = f32x4{0.f, 0.f, 0.f, 0.f};
        oacc[1] = f32x4{0.f, 0.f, 0.f, 0.f};
        #pragma unroll
        for (int kt = 0; kt < 4; ++kt) {
            const int ko = FI + kt * 32 + quad * 8;
            bf16x8 b0 = *(const bf16x8*)&inpT[l16 * SI + ko];
            bf16x8 b1 = *(const bf16x8*)&inpT[(16 + l16) * SI + ko];
            oacc[0] = mfma16(oA[kt], b0, oacc[0]);
            oacc[1] = mfma16(oA[kt], b1, oacc[1]);
        }
        float* ostage = zbuf;  // z fully consumed before barrier 5 -> safe reuse
        #pragma unroll
        for (int nt = 0; nt < 2; ++nt)
        #pragma unroll
        for (int r = 0; r < 4; ++r) {
            const int row = wave * 16 + quad * 4 + r;
            const int col = nt * 16 + l16;
            const float v = oacc[nt][r] + bias[GG + HH + row];
            ostage[col * SO + row] = v > 0.0f ? v : 0.0f;
        }
        __syncthreads();                                   // 6: staging complete
        float* op = obase + (size_t)t * N_ * FI + xcol * FI + xcg;
        *(f32x4*)op       = *(const f32x4*)&ostage[xcol * SO + xcg];
        *(f32x4*)(op + 4) = *(const f32x4*)&ostage[xcol * SO + xcg + 4];
    }
}

extern "C" void kernel_launch(void* const* d_in, const int* in_sizes, int n_in,
                              void* d_out, int out_size, void* d_ws, size_t ws_size,
                              hipStream_t stream) {
    (void)in_sizes; (void)n_in; (void)d_ws; (void)ws_size; (void)out_size;
    const float* x      = (const float*)d_in[0];
    const float* gate_w = (const float*)d_in[1];
    const float* gate_b = (const float*)d_in[2];
    const float* cand_w = (const float*)d_in[3];
    const float* cand_b = (const float*)d_in[4];
    const float* out_w  = (const float*)d_in[5];
    const float* out_b  = (const float*)d_in[6];
    float* out = (float*)d_out;
    mgru_kernel<<<dim3(B_ * (N_ / COLS)), dim3(256), 0, stream>>>(
        x, gate_w, gate_b, cand_w, cand_b, out_w, out_b, out);
}

// Round 2
// 568.114 us; speedup vs baseline: 1.0922x; 1.0922x over previous
//
#include <hip/hip_runtime.h>

#define B_ 8
#define T_ 24
#define N_ 4096
#define FI 64
#define HH 128
#define CC 192
#define COLS 64
#define SI 200   // inpT stride (bf16): 400B = 16B-aligned; b128 reads land at provable bank minimum
#define SC 136   // cinpT stride (bf16): 272B = 16B-aligned; same

typedef __bf16 bf16_t;
typedef bf16_t bf16x8 __attribute__((ext_vector_type(8)));
typedef bf16_t bf16x4 __attribute__((ext_vector_type(4)));
typedef float  f32x4  __attribute__((ext_vector_type(4)));

static __device__ __forceinline__ f32x4 mfma16(bf16x8 a, bf16x8 b, f32x4 c) {
    return __builtin_amdgcn_mfma_f32_16x16x32_bf16(a, b, c, 0, 0, 0);
}

// Wave/row assignment (8 waves, 64 cols):
//   gates (256 rows, 16 M-tiles): wave w owns M-tiles {w}   -> r rows  w*16..w*16+15
//                                              and   {8+w}  -> z rows 128+w*16..
//   cand  (128 rows,  8 M-tiles): wave w owns M-tile  {w}   -> rows    w*16..w*16+15
//   => the lane computing cand(ch,col) also holds r(ch,col), z(ch,col), h(ch,col)
//      in registers: no LDS for z or fp32-h at all.
//   out   (64 rows, 4 M-tiles x 4 N-tiles = 16 mfma): wave w -> M-tile w>>1, N-tiles (w&1)*2+{0,1}
__global__ __launch_bounds__(512, 2) void mgru_kernel(
    const float* __restrict__ x,
    const float* __restrict__ gate_w,
    const float* __restrict__ gate_b,
    const float* __restrict__ cand_w,
    const float* __restrict__ cand_b,
    const float* __restrict__ out_w,
    const float* __restrict__ out_b,
    float* __restrict__ out)
{
    __shared__ __align__(16) bf16_t inpT[COLS * SI];   // [col][ch]: 0..63 = x_t, 64..191 = h (bf16 feed)
    __shared__ __align__(16) bf16_t cinpT[COLS * SC];  // [col][ch]: 0..127 = r*h (bf16 feed)

    const int tid  = threadIdx.x;
    const int wave = tid >> 6;          // 0..7
    const int lane = tid & 63;
    const int quad = lane >> 4;
    const int l16  = lane & 15;

    const int bb = blockIdx.x >> 6;           // batch
    const int n0 = (blockIdx.x & 63) * COLS;  // column tile base

    // zero the h region of inpT (h0 = 0)
    for (int i = tid; i < COLS * HH; i += 512) {
        const int col = i >> 7, ch = i & (HH - 1);
        inpT[col * SI + FI + ch] = (bf16_t)0.0f;
    }

    // ---- weights -> register A-fragments (lane holds A[m0+l16][k0+quad*8+j]) ----
    bf16x8 gA[2][6];   // p=0: r M-tile (rows w*16+..), p=1: z M-tile (rows 128+w*16+..)
    #pragma unroll
    for (int p = 0; p < 2; ++p) {
        const int m = p * 128 + wave * 16 + l16;
        #pragma unroll
        for (int kt = 0; kt < 6; ++kt) {
            bf16x8 f;
            #pragma unroll
            for (int j = 0; j < 8; ++j)
                f[j] = (bf16_t)gate_w[(m * CC + kt * 32 + quad * 8 + j) * 2 + 1];
            gA[p][kt] = f;
        }
    }
    bf16x8 cA[6];
    {
        const int m = wave * 16 + l16;
        #pragma unroll
        for (int kt = 0; kt < 6; ++kt) {
            bf16x8 f;
            #pragma unroll
            for (int j = 0; j < 8; ++j)
                f[j] = (bf16_t)cand_w[(m * CC + kt * 32 + quad * 8 + j) * 2 + 1];
            cA[kt] = f;
        }
    }
    bf16x8 oA[4];
    {
        const int m = (wave >> 1) * 16 + l16;
        #pragma unroll
        for (int kt = 0; kt < 4; ++kt) {
            bf16x8 f;
            #pragma unroll
            for (int j = 0; j < 8; ++j)
                f[j] = (bf16_t)out_w[m * HH + kt * 32 + quad * 8 + j];
            oA[kt] = f;
        }
    }

    // ---- biases -> registers (folded into accumulator init; per-r, col-independent) ----
    f32x4 gBr, gBz, cB, oB;
    #pragma unroll
    for (int r = 0; r < 4; ++r) {
        gBr[r] = gate_b[wave * 16 + quad * 4 + r];
        gBz[r] = gate_b[128 + wave * 16 + quad * 4 + r];
        cB[r]  = cand_b[wave * 16 + quad * 4 + r];
        oB[r]  = out_b[(wave >> 1) * 16 + quad * 4 + r];
    }

    // fp32 master h, fully register-resident: hreg[nt][r] = h[wave*16+quad*4+r][nt*16+l16]
    f32x4 hreg[4];
    #pragma unroll
    for (int nt = 0; nt < 4; ++nt) hreg[nt] = f32x4{0.f, 0.f, 0.f, 0.f};

    const int xcol = tid >> 3;          // 0..63
    const int xcg  = (tid & 7) * 8;     // 8-float group of the 64 features
    const float* xbase = x   + ((size_t)bb * T_ * N_ + n0) * FI;
    float*       obase = out + ((size_t)bb * T_ * N_ + n0) * FI;

    // prefetch x_0
    f32x4 p0 = *(const f32x4*)(xbase + xcol * FI + xcg);
    f32x4 p1 = *(const f32x4*)(xbase + xcol * FI + xcg + 4);

    for (int t = 0; t < T_; ++t) {
        // ---- stage x_t (from prefetch regs) -> bf16 LDS; then prefetch x_{t+1} ----
        {
            bf16x8 xv;
            xv[0] = (bf16_t)p0[0]; xv[1] = (bf16_t)p0[1];
            xv[2] = (bf16_t)p0[2]; xv[3] = (bf16_t)p0[3];
            xv[4] = (bf16_t)p1[0]; xv[5] = (bf16_t)p1[1];
            xv[6] = (bf16_t)p1[2]; xv[7] = (bf16_t)p1[3];
            *(bf16x8*)&inpT[xcol * SI + xcg] = xv;
        }
        {
            const int tn = (t + 1 < T_) ? t + 1 : t;
            const float* xp = xbase + (size_t)tn * N_ * FI + xcol * FI + xcg;
            p0 = *(const f32x4*)xp;
            p1 = *(const f32x4*)(xp + 4);
        }
        __syncthreads();                                   // B1: x ready (h from prev step)

        // ---- gates = Wg @ [x; h]  (r and z M-tiles, 4 col-tiles) ----
        f32x4 ar[4], az[4];
        #pragma unroll
        for (int nt = 0; nt < 4; ++nt) { ar[nt] = gBr; az[nt] = gBz; }
        #pragma unroll
        for (int kt = 0; kt < 6; ++kt) {
            const int ko = kt * 32 + quad * 8;
            bf16x8 b[4];
            #pragma unroll
            for (int nt = 0; nt < 4; ++nt)
                b[nt] = *(const bf16x8*)&inpT[(nt * 16 + l16) * SI + ko];
            #pragma unroll
            for (int nt = 0; nt < 4; ++nt) {
                ar[nt] = mfma16(gA[0][kt], b[nt], ar[nt]);
                az[nt] = mfma16(gA[1][kt], b[nt], az[nt]);
            }
        }
        // sigmoid; r*h -> cinpT (bf16); z stays in registers
        f32x4 zreg[4];
        #pragma unroll
        for (int nt = 0; nt < 4; ++nt) {
            bf16x4 w;
            #pragma unroll
            for (int r = 0; r < 4; ++r) {
                const float rr = 1.0f / (1.0f + __expf(-ar[nt][r]));
                zreg[nt][r]    = 1.0f / (1.0f + __expf(-az[nt][r]));
                w[r] = (bf16_t)(rr * hreg[nt][r]);
            }
            *(bf16x4*)&cinpT[(nt * 16 + l16) * SC + wave * 16 + quad * 4] = w;
        }
        __syncthreads();                                   // B2: r*h ready

        // ---- cand = Wc @ [x; r*h] ----
        f32x4 cc[4];
        #pragma unroll
        for (int nt = 0; nt < 4; ++nt) cc[nt] = cB;
        #pragma unroll
        for (int kt = 0; kt < 6; ++kt) {
            const int ko = kt * 32 + quad * 8;
            #pragma unroll
            for (int nt = 0; nt < 4; ++nt) {
                bf16x8 b = (kt < 2)
                    ? *(const bf16x8*)&inpT[(nt * 16 + l16) * SI + ko]
                    : *(const bf16x8*)&cinpT[(nt * 16 + l16) * SC + (ko - FI)];
                cc[nt] = mfma16(cA[kt], b, cc[nt]);
            }
        }
        // tanh + state update (all in registers); refresh bf16 h in inpT
        #pragma unroll
        for (int nt = 0; nt < 4; ++nt) {
            bf16x4 hw;
            #pragma unroll
            for (int r = 0; r < 4; ++r) {
                const float v  = cc[nt][r];
                const float e  = __expf(2.0f * v);
                const float ht = 1.0f - 2.0f / (e + 1.0f);     // tanh(v)
                const float z  = zreg[nt][r];
                const float h  = hreg[nt][r];
                const float hn = h + z * (ht - h);             // (1-z)h + z*ht
                hreg[nt][r] = hn;
                hw[r] = (bf16_t)hn;
            }
            *(bf16x4*)&inpT[(nt * 16 + l16) * SI + FI + wave * 16 + quad * 4] = hw;
        }
        __syncthreads();                                   // B3: h_t ready

        // ---- o = relu(Wo @ h_t + b) -> direct global store from D-fragments ----
        {
            f32x4 oa[2];
            oa[0] = oB; oa[1] = oB;
            const int nb = (wave & 1) * 2;
            #pragma unroll
            for (int kt = 0; kt < 4; ++kt) {
                const int ko = FI + kt * 32 + quad * 8;
                bf16x8 b0 = *(const bf16x8*)&inpT[(nb * 16 + l16) * SI + ko];
                bf16x8 b1 = *(const bf16x8*)&inpT[((nb + 1) * 16 + l16) * SI + ko];
                oa[0] = mfma16(oA[kt], b0, oa[0]);
                oa[1] = mfma16(oA[kt], b1, oa[1]);
            }
            #pragma unroll
            for (int j = 0; j < 2; ++j) {
                const int col = (nb + j) * 16 + l16;
                float* op = obase + (size_t)t * N_ * FI + col * FI + (wave >> 1) * 16 + quad * 4;
                f32x4 o;
                #pragma unroll
                for (int r = 0; r < 4; ++r) o[r] = fmaxf(oa[j][r], 0.0f);
                *(f32x4*)op = o;
            }
        }
    }
}

extern "C" void kernel_launch(void* const* d_in, const int* in_sizes, int n_in,
                              void* d_out, int out_size, void* d_ws, size_t ws_size,
                              hipStream_t stream) {
    (void)in_sizes; (void)n_in; (void)d_ws; (void)ws_size; (void)out_size;
    const float* x      = (const float*)d_in[0];
    const float* gate_w = (const float*)d_in[1];
    const float* gate_b = (const float*)d_in[2];
    const float* cand_w = (const float*)d_in[3];
    const float* cand_b = (const float*)d_in[4];
    const float* out_w  = (const float*)d_in[5];
    const float* out_b  = (const float*)d_in[6];
    float* out = (float*)d_out;
    mgru_kernel<<<dim3(B_ * (N_ / COLS)), dim3(512), 0, stream>>>(
        x, gate_w, gate_b, cand_w, cand_b, out_w, out_b, out);
}